// Round 13
// baseline (350.673 us; speedup 1.0000x reference)
//
#include <hip/hip_runtime.h>

// FinePreprocess: bilinear 8x8 crops of 32-channel feature maps at 2048
// sub-pixel track points per view, 16 views.
//
// features      : (1, 16, 32, 512, 512) f32   -> d_in[0]
// sample_points : (1, 16, 2048, 2)      f32   -> d_in[1]  (x, y), interior
// img_idxs      : (1, 16, 2048)         int   -> d_in[2]  (0..15)
// out           : (1, 16, 2048, 64, 32) f32   -> d_out
//
// Two-phase (R10/R11): CHW f32 -> HWC bf16 transform in d_ws (phase A, at
// its BW roofline: 768MB @ ~6TB/s), then channel-contiguous gather (B).
// Cache discipline: nt-loads for the f32 stream, nt-stores for out.
//
// R12 null: batching 12 loads in flight didn't move phase B -> not
// latency/MLP-bound. R13 tests the VMEM-INSTRUCTION-RATE hypothesis:
// 2 consecutive tracks per wave, lane = (half=track, p=crop col, o=ch
// octet); tap loads widen uint2 -> uint4 (16B = 8 ch) and each load
// instruction serves both tracks: 20 -> 10 load instr/track. Stores stay
// 8/track (2 x f32x4 per lane per row; tracks 2t,2t+1 have adjacent 8KB
// slots -> still fully contiguous). Row-select branches become half-
// divergent (exec-masked both paths; VALU at 6%, harmless). VGPR ~70 ->
// launch_bounds(256,6).
//
// Row-window math (R6, per track): taps in rows B0..B0+9, B0=floor(py-4);
// for crop row r, y0-B0 in {K,K+1}, K=floor(8r/7); lin[0]/lin[7] forced
// exact (+/-4). Taps provably interior ([3,509]) -> no masks/clamps.
// bf16 taps: absmax 0.031 << 0.1 threshold (R10-R12).

#define CROP    8
#define C_CH    32
#define H_DIM   512
#define W_DIM   512
#define HW_SZ   (H_DIM * W_DIM)
#define N_VIEWS 16
#define TPB     4   // waves per block; 2 tracks per wave

typedef float f32x4 __attribute__((ext_vector_type(4)));

__device__ __forceinline__ unsigned short f2bf(float f) {
    unsigned int u = __float_as_uint(f);
    u = (u + 0x7fffu + ((u >> 16) & 1u)) >> 16;
    return (unsigned short)u;
}
__device__ __forceinline__ float bf_lo(unsigned int u) {
    return __uint_as_float(u << 16);
}
__device__ __forceinline__ float bf_hi(unsigned int u) {
    return __uint_as_float(u & 0xffff0000u);
}

// ---------------- Phase A: CHW f32 -> HWC bf16 (unchanged, at BW roof) ----
__global__ __launch_bounds__(256) void chw_to_hwc_bf16(
    const float* __restrict__ feat,     // (16, 32, 512, 512)
    unsigned short* __restrict__ hwc)   // (16, 512, 512, 32)
{
    const int xb  = blockIdx.x;         // 0..1
    const int y   = blockIdx.y;         // 0..511
    const int v   = blockIdx.z;         // 0..15
    const int tid = threadIdx.x;        // 0..255

    __shared__ float lds[C_CH][257];

    const int px0 = xb * 256;
    const size_t rbase =
        (size_t)v * C_CH * HW_SZ + (size_t)y * W_DIM + px0;

    #pragma unroll
    for (int c = 0; c < C_CH; ++c)
        lds[c][tid] =
            __builtin_nontemporal_load(feat + rbase + (size_t)c * HW_SZ + tid);

    __syncthreads();

    unsigned short* __restrict__ wbase =
        hwc + (((size_t)v * H_DIM + y) * W_DIM + px0) * C_CH;
    const int c0 = (tid & 7) * 4;

    #pragma unroll
    for (int pp = 0; pp < 8; ++pp) {
        const int px = pp * 32 + (tid >> 3);
        uint2 o;
        o.x = (unsigned int)f2bf(lds[c0 + 0][px]) |
              ((unsigned int)f2bf(lds[c0 + 1][px]) << 16);
        o.y = (unsigned int)f2bf(lds[c0 + 2][px]) |
              ((unsigned int)f2bf(lds[c0 + 3][px]) << 16);
        *reinterpret_cast<uint2*>(wbase + (size_t)px * C_CH + c0) = o;
    }
}

// ---------------- Phase B: 2-track/wave gather from HWC bf16 ------------
// lane = half*32 + p*4 + o : half = track in pair, p = crop col 0..7,
// o = channel octet 0..3 (8 bf16 channels = one uint4 tap load).
__global__ __launch_bounds__(256, 6) void gather_hwc(
    const unsigned short* __restrict__ hwc,
    const float* __restrict__ pts,
    const int*   __restrict__ bids,
    float*       __restrict__ out,
    int n_tracks)
{
    const int wid  = threadIdx.x >> 6;
    const int lane = threadIdx.x & 63;
    const int half = lane >> 5;
    const int l5   = lane & 31;
    const int p    = l5 >> 2;          // crop column 0..7
    const int o8   = (l5 & 3) << 3;    // channel octet base 0,8,16,24

    const int t = (blockIdx.x * TPB + wid) * 2 + half;
    if (t >= n_tracks) return;

    const float px = pts[2 * t];
    const float py = pts[2 * t + 1];
    const int   b  = bids[t];

    const float linx = (p == 7) ? 4.0f : fmaf((float)p, 8.0f / 7.0f, -4.0f);
    const float X   = px + linx;
    const float x0f = floorf(X);
    const float wx  = X - x0f;
    const int   x0  = (int)x0f;

    const int B0 = (int)floorf(py - 4.0f);   // per-track top tap row

    const size_t rowstride = (size_t)W_DIM * C_CH;
    const unsigned short* __restrict__ hb =
        hwc + (size_t)b * HW_SZ * C_CH + (size_t)B0 * rowstride
            + (size_t)x0 * C_CH + o8;

    float* __restrict__ obase =
        out + (size_t)t * (CROP * CROP * C_CH) + p * C_CH + o8;

    // Tap window: ua[j] = 8ch at (row j, x0), ub[j] = 8ch at (row j, x0+1).
    uint4 ua[6], ub[6];

    // ---- preload rows B0..B0+5: 12 uint4 loads (serve both tracks) ----
    #pragma unroll
    for (int j = 0; j < 6; ++j) {
        ua[j] = *reinterpret_cast<const uint4*>(hb + (size_t)j * rowstride);
        ub[j] = *reinterpret_cast<const uint4*>(hb + (size_t)j * rowstride + C_CH);
    }

#define EMIT(r, ja, jb, wy_) do {                                             \
    const float wy__ = (wy_);                                                 \
    const float w00 = (1.0f - wy__) * (1.0f - wx);                            \
    const float w01 = (1.0f - wy__) * wx;                                     \
    const float w10 = wy__ * (1.0f - wx);                                     \
    const float w11 = wy__ * wx;                                              \
    f32x4 o0, o1;                                                             \
    o0.x = fmaf(bf_lo(ua[ja].x), w00, fmaf(bf_lo(ub[ja].x), w01,              \
           fmaf(bf_lo(ua[jb].x), w10, bf_lo(ub[jb].x) * w11)));               \
    o0.y = fmaf(bf_hi(ua[ja].x), w00, fmaf(bf_hi(ub[ja].x), w01,              \
           fmaf(bf_hi(ua[jb].x), w10, bf_hi(ub[jb].x) * w11)));               \
    o0.z = fmaf(bf_lo(ua[ja].y), w00, fmaf(bf_lo(ub[ja].y), w01,              \
           fmaf(bf_lo(ua[jb].y), w10, bf_lo(ub[jb].y) * w11)));               \
    o0.w = fmaf(bf_hi(ua[ja].y), w00, fmaf(bf_hi(ub[ja].y), w01,              \
           fmaf(bf_hi(ua[jb].y), w10, bf_hi(ub[jb].y) * w11)));               \
    o1.x = fmaf(bf_lo(ua[ja].z), w00, fmaf(bf_lo(ub[ja].z), w01,              \
           fmaf(bf_lo(ua[jb].z), w10, bf_lo(ub[jb].z) * w11)));               \
    o1.y = fmaf(bf_hi(ua[ja].z), w00, fmaf(bf_hi(ub[ja].z), w01,              \
           fmaf(bf_hi(ua[jb].z), w10, bf_hi(ub[jb].z) * w11)));               \
    o1.z = fmaf(bf_lo(ua[ja].w), w00, fmaf(bf_lo(ub[ja].w), w01,              \
           fmaf(bf_lo(ua[jb].w), w10, bf_lo(ub[jb].w) * w11)));               \
    o1.w = fmaf(bf_hi(ua[ja].w), w00, fmaf(bf_hi(ub[ja].w), w01,              \
           fmaf(bf_hi(ua[jb].w), w10, bf_hi(ub[jb].w) * w11)));               \
    __builtin_nontemporal_store(o0,                                           \
        reinterpret_cast<f32x4*>(obase + (r) * 256));                         \
    __builtin_nontemporal_store(o1,                                           \
        reinterpret_cast<f32x4*>(obase + (r) * 256 + 4));                     \
} while (0)

    { const float wy = (py - 4.0f) - (float)B0; EMIT(0, 0, 1, wy); }

#define ROW_P1(r, K) do {                                                     \
    const float Y   = py + fmaf((float)(r), 8.0f / 7.0f, -4.0f);              \
    const float y0f = floorf(Y);                                              \
    const float wy  = Y - y0f;                                                \
    if ((int)y0f - B0 == (K)) EMIT(r, (K), (K) + 1, wy);                      \
    else                      EMIT(r, (K) + 1, (K) + 2, wy);                  \
} while (0)

    ROW_P1(1, 1);
    ROW_P1(2, 2);
    ROW_P1(3, 3);

    // ---- shift rows 4,5 -> 0,1; preload rows B0+6..B0+9 ----
    ua[0] = ua[4]; ub[0] = ub[4];
    ua[1] = ua[5]; ub[1] = ub[5];
    #pragma unroll
    for (int j = 2; j < 6; ++j) {
        ua[j] = *reinterpret_cast<const uint4*>(hb + (size_t)(j + 4) * rowstride);
        ub[j] = *reinterpret_cast<const uint4*>(hb + (size_t)(j + 4) * rowstride + C_CH);
    }

#define ROW_P2(r, K) do {                                                     \
    const float Y   = py + fmaf((float)(r), 8.0f / 7.0f, -4.0f);              \
    const float y0f = floorf(Y);                                              \
    const float wy  = Y - y0f;                                                \
    if ((int)y0f - B0 == (K) + 4) EMIT(r, (K), (K) + 1, wy);                  \
    else                          EMIT(r, (K) + 1, (K) + 2, wy);              \
} while (0)

    ROW_P2(4, 0);
    ROW_P2(5, 1);
    ROW_P2(6, 2);

    { const float wy = (py + 4.0f) - (float)(B0 + 8); EMIT(7, 4, 5, wy); }
}

// ---------------- Fallback: plain CHW-f32 gather (R9 body) ----------------
__global__ __launch_bounds__(256, 8) void fallback_kernel(
    const float* __restrict__ feat,
    const float* __restrict__ pts,
    const int*   __restrict__ bids,
    float*       __restrict__ out,
    int n_tracks)
{
    const int wid  = threadIdx.x >> 6;
    const int lane = threadIdx.x & 63;
    const int t    = blockIdx.x * TPB + wid;
    if (t >= n_tracks) return;

    const int cx = lane >> 3;
    const int c0 = (lane & 7) << 2;

    const float px = pts[2 * t];
    const float py = pts[2 * t + 1];
    const int   b  = bids[t];

    const float linx = (cx == 7) ? 4.0f : fmaf((float)cx, 8.0f / 7.0f, -4.0f);
    const float X   = px + linx;
    const float x0f = floorf(X);
    const float wx  = X - x0f;
    const int   x0  = (int)x0f;

    float* __restrict__ obase =
        out + (size_t)t * (CROP * CROP * C_CH) + lane * 4;

    const float* __restrict__ fp =
        feat + ((size_t)b * C_CH + c0) * HW_SZ + x0;

    #pragma unroll 2
    for (int r = 0; r < CROP; ++r) {
        const float Y = (r == 0) ? (py - 4.0f)
                      : (r == 7) ? (py + 4.0f)
                      : py + fmaf((float)r, 8.0f / 7.0f, -4.0f);
        const float y0f = floorf(Y);
        const float wy  = Y - y0f;
        const int   y0  = (int)y0f;

        const int r0 = y0 * W_DIM;
        const int r1 = r0 + W_DIM;

        const float w00 = (1.0f - wy) * (1.0f - wx);
        const float w01 = (1.0f - wy) * wx;
        const float w10 = wy * (1.0f - wx);
        const float w11 = wy * wx;

        f32x4 o;
        #pragma unroll
        for (int cc = 0; cc < 4; ++cc) {
            const int off = cc * HW_SZ;
            o[cc] = fmaf(fp[r0 + off], w00, fmaf(fp[r0 + off + 1], w01,
                    fmaf(fp[r1 + off], w10, fp[r1 + off + 1] * w11)));
        }
        *reinterpret_cast<f32x4*>(obase + r * 256) = o;
    }
}

extern "C" void kernel_launch(void* const* d_in, const int* in_sizes, int n_in,
                              void* d_out, int out_size, void* d_ws, size_t ws_size,
                              hipStream_t stream) {
    const float* feat = (const float*)d_in[0];
    const float* pts  = (const float*)d_in[1];
    const int*   bids = (const int*)d_in[2];
    float*       out  = (float*)d_out;

    const int n_tracks = in_sizes[2];   // 32768

    const size_t hwc_bytes =
        (size_t)N_VIEWS * H_DIM * W_DIM * C_CH * sizeof(unsigned short);

    if (ws_size >= hwc_bytes) {
        unsigned short* hwc = (unsigned short*)d_ws;
        chw_to_hwc_bf16<<<dim3(2, H_DIM, N_VIEWS), 256, 0, stream>>>(feat, hwc);
        const int tracks_per_block = TPB * 2;
        const int blocks = (n_tracks + tracks_per_block - 1) / tracks_per_block;
        gather_hwc<<<blocks, TPB * 64, 0, stream>>>(hwc, pts, bids, out,
                                                    n_tracks);
    } else {
        const int blocks = (n_tracks + TPB - 1) / TPB;
        fallback_kernel<<<blocks, TPB * 64, 0, stream>>>(feat, pts, bids, out,
                                                         n_tracks);
    }
}

// Round 14
// 205.552 us; speedup vs baseline: 1.7060x; 1.7060x over previous
//
#include <hip/hip_runtime.h>

// FinePreprocess: bilinear 8x8 crops of 32-channel feature maps at 2048
// sub-pixel track points per view, 16 views.
//
// features      : (1, 16, 32, 512, 512) f32   -> d_in[0]
// sample_points : (1, 16, 2048, 2)      f32   -> d_in[1]  (x, y), interior
// img_idxs      : (1, 16, 2048)         int   -> d_in[2]  (0..15)
// out           : (1, 16, 2048, 64, 32) f32   -> d_out
//
// FINAL (R12 state, reverted from R13's divergence regression).
// Two-phase: CHW f32 -> HWC bf16 transform in d_ws (phase A, at its BW
// roofline: 768MB @ ~6TB/s), then channel-contiguous gather (phase B,
// ~7.8TB/s combined L3-read + HBM-write mix).
// Cache discipline: nt-loads for the f32 stream (A), nt-stores for out (B)
// -> hwc stays L3-resident for B's tap reads.
// R13 lesson: do NOT pack 2 tracks/wave -- per-track row-select branches
// diverge and execute both register-pair paths per EMIT (~2x instr issue).
//
// Row-window math (R6): taps in rows B0..B0+9, B0=floor(py-4); for crop
// row r, y0-B0 in {K,K+1}, K=floor(8r/7); lin[0]/lin[7] forced exact
// (+/-4). Taps provably interior ([3,509]) -> no masks/clamps.
// bf16 taps: absmax 0.031 << 0.1 threshold (R10-R12).

#define CROP    8
#define C_CH    32
#define H_DIM   512
#define W_DIM   512
#define HW_SZ   (H_DIM * W_DIM)
#define N_VIEWS 16
#define TPB     4

typedef float f32x4 __attribute__((ext_vector_type(4)));

__device__ __forceinline__ unsigned short f2bf(float f) {
    unsigned int u = __float_as_uint(f);
    u = (u + 0x7fffu + ((u >> 16) & 1u)) >> 16;
    return (unsigned short)u;
}
__device__ __forceinline__ float bf_lo(unsigned int u) {
    return __uint_as_float(u << 16);
}
__device__ __forceinline__ float bf_hi(unsigned int u) {
    return __uint_as_float(u & 0xffff0000u);
}

// ---------------- Phase A: CHW f32 -> HWC bf16 (at BW roofline) ----------
__global__ __launch_bounds__(256) void chw_to_hwc_bf16(
    const float* __restrict__ feat,     // (16, 32, 512, 512)
    unsigned short* __restrict__ hwc)   // (16, 512, 512, 32)
{
    const int xb  = blockIdx.x;         // 0..1
    const int y   = blockIdx.y;         // 0..511
    const int v   = blockIdx.z;         // 0..15
    const int tid = threadIdx.x;        // 0..255

    __shared__ float lds[C_CH][257];

    const int px0 = xb * 256;
    const size_t rbase =
        (size_t)v * C_CH * HW_SZ + (size_t)y * W_DIM + px0;

    #pragma unroll
    for (int c = 0; c < C_CH; ++c)
        lds[c][tid] =
            __builtin_nontemporal_load(feat + rbase + (size_t)c * HW_SZ + tid);

    __syncthreads();

    unsigned short* __restrict__ wbase =
        hwc + (((size_t)v * H_DIM + y) * W_DIM + px0) * C_CH;
    const int c0 = (tid & 7) * 4;

    #pragma unroll
    for (int pp = 0; pp < 8; ++pp) {
        const int px = pp * 32 + (tid >> 3);
        uint2 o;
        o.x = (unsigned int)f2bf(lds[c0 + 0][px]) |
              ((unsigned int)f2bf(lds[c0 + 1][px]) << 16);
        o.y = (unsigned int)f2bf(lds[c0 + 2][px]) |
              ((unsigned int)f2bf(lds[c0 + 3][px]) << 16);
        *reinterpret_cast<uint2*>(wbase + (size_t)px * C_CH + c0) = o;
    }
}

// ---------------- Phase B: batched-window gather from HWC bf16 ----------
// One wave per track, lane = (p = lane>>3 crop col, g = lane&7 ch-quad).
__global__ __launch_bounds__(256, 8) void gather_hwc(
    const unsigned short* __restrict__ hwc,
    const float* __restrict__ pts,
    const int*   __restrict__ bids,
    float*       __restrict__ out,
    int n_tracks)
{
    const int wid  = threadIdx.x >> 6;
    const int lane = threadIdx.x & 63;
    const int t    = blockIdx.x * TPB + wid;
    if (t >= n_tracks) return;

    const int p  = lane >> 3;
    const int c0 = (lane & 7) << 2;

    const float px = pts[2 * t];
    const float py = pts[2 * t + 1];
    const int   b  = bids[t];

    const float linx = (p == 7) ? 4.0f : fmaf((float)p, 8.0f / 7.0f, -4.0f);
    const float X   = px + linx;
    const float x0f = floorf(X);
    const float wx  = X - x0f;
    const int   x0  = (int)x0f;

    const int B0 = (int)floorf(py - 4.0f);   // wave-uniform top tap row

    const size_t rowstride = (size_t)W_DIM * C_CH;
    const unsigned short* __restrict__ hb =
        hwc + (size_t)b * HW_SZ * C_CH + (size_t)B0 * rowstride
            + (size_t)x0 * C_CH + c0;

    float* __restrict__ obase =
        out + (size_t)t * (CROP * CROP * C_CH) + lane * 4;

    // Tap window: ua[j] = taps at (row j, x0), ub[j] = (row j, x0+1)
    uint2 ua[6], ub[6];

    // ---- preload rows B0..B0+5: 12 independent uint2 loads ----
    #pragma unroll
    for (int j = 0; j < 6; ++j) {
        ua[j] = *reinterpret_cast<const uint2*>(hb + (size_t)j * rowstride);
        ub[j] = *reinterpret_cast<const uint2*>(hb + (size_t)j * rowstride + C_CH);
    }

#define EMIT(r, ja, jb, wy_) do {                                             \
    const float wy__ = (wy_);                                                 \
    const float w00 = (1.0f - wy__) * (1.0f - wx);                            \
    const float w01 = (1.0f - wy__) * wx;                                     \
    const float w10 = wy__ * (1.0f - wx);                                     \
    const float w11 = wy__ * wx;                                              \
    f32x4 o;                                                                  \
    o.x = fmaf(bf_lo(ua[ja].x), w00, fmaf(bf_lo(ub[ja].x), w01,               \
          fmaf(bf_lo(ua[jb].x), w10, bf_lo(ub[jb].x) * w11)));                \
    o.y = fmaf(bf_hi(ua[ja].x), w00, fmaf(bf_hi(ub[ja].x), w01,               \
          fmaf(bf_hi(ua[jb].x), w10, bf_hi(ub[jb].x) * w11)));                \
    o.z = fmaf(bf_lo(ua[ja].y), w00, fmaf(bf_lo(ub[ja].y), w01,               \
          fmaf(bf_lo(ua[jb].y), w10, bf_lo(ub[jb].y) * w11)));                \
    o.w = fmaf(bf_hi(ua[ja].y), w00, fmaf(bf_hi(ub[ja].y), w01,               \
          fmaf(bf_hi(ua[jb].y), w10, bf_hi(ub[jb].y) * w11)));                \
    __builtin_nontemporal_store(o,                                            \
        reinterpret_cast<f32x4*>(obase + (r) * 256));                         \
} while (0)

    { const float wy = (py - 4.0f) - (float)B0; EMIT(0, 0, 1, wy); }

#define ROW_P1(r, K) do {                                                     \
    const float Y   = py + fmaf((float)(r), 8.0f / 7.0f, -4.0f);              \
    const float y0f = floorf(Y);                                              \
    const float wy  = Y - y0f;                                                \
    if ((int)y0f - B0 == (K)) EMIT(r, (K), (K) + 1, wy);                      \
    else                      EMIT(r, (K) + 1, (K) + 2, wy);                  \
} while (0)

    ROW_P1(1, 1);
    ROW_P1(2, 2);
    ROW_P1(3, 3);

    // ---- shift rows 4,5 -> 0,1; preload rows B0+6..B0+9 ----
    ua[0] = ua[4]; ub[0] = ub[4];
    ua[1] = ua[5]; ub[1] = ub[5];
    #pragma unroll
    for (int j = 2; j < 6; ++j) {
        ua[j] = *reinterpret_cast<const uint2*>(hb + (size_t)(j + 4) * rowstride);
        ub[j] = *reinterpret_cast<const uint2*>(hb + (size_t)(j + 4) * rowstride + C_CH);
    }

#define ROW_P2(r, K) do {                                                     \
    const float Y   = py + fmaf((float)(r), 8.0f / 7.0f, -4.0f);              \
    const float y0f = floorf(Y);                                              \
    const float wy  = Y - y0f;                                                \
    if ((int)y0f - B0 == (K) + 4) EMIT(r, (K), (K) + 1, wy);                  \
    else                          EMIT(r, (K) + 1, (K) + 2, wy);              \
} while (0)

    ROW_P2(4, 0);
    ROW_P2(5, 1);
    ROW_P2(6, 2);

    { const float wy = (py + 4.0f) - (float)(B0 + 8); EMIT(7, 4, 5, wy); }
}

// ---------------- Fallback: plain CHW-f32 gather (R9 body) ----------------
__global__ __launch_bounds__(256, 8) void fallback_kernel(
    const float* __restrict__ feat,
    const float* __restrict__ pts,
    const int*   __restrict__ bids,
    float*       __restrict__ out,
    int n_tracks)
{
    const int wid  = threadIdx.x >> 6;
    const int lane = threadIdx.x & 63;
    const int t    = blockIdx.x * TPB + wid;
    if (t >= n_tracks) return;

    const int cx = lane >> 3;
    const int c0 = (lane & 7) << 2;

    const float px = pts[2 * t];
    const float py = pts[2 * t + 1];
    const int   b  = bids[t];

    const float linx = (cx == 7) ? 4.0f : fmaf((float)cx, 8.0f / 7.0f, -4.0f);
    const float X   = px + linx;
    const float x0f = floorf(X);
    const float wx  = X - x0f;
    const int   x0  = (int)x0f;

    float* __restrict__ obase =
        out + (size_t)t * (CROP * CROP * C_CH) + lane * 4;

    const float* __restrict__ fp =
        feat + ((size_t)b * C_CH + c0) * HW_SZ + x0;

    #pragma unroll 2
    for (int r = 0; r < CROP; ++r) {
        const float Y = (r == 0) ? (py - 4.0f)
                      : (r == 7) ? (py + 4.0f)
                      : py + fmaf((float)r, 8.0f / 7.0f, -4.0f);
        const float y0f = floorf(Y);
        const float wy  = Y - y0f;
        const int   y0  = (int)y0f;

        const int r0 = y0 * W_DIM;
        const int r1 = r0 + W_DIM;

        const float w00 = (1.0f - wy) * (1.0f - wx);
        const float w01 = (1.0f - wy) * wx;
        const float w10 = wy * (1.0f - wx);
        const float w11 = wy * wx;

        f32x4 o;
        #pragma unroll
        for (int cc = 0; cc < 4; ++cc) {
            const int off = cc * HW_SZ;
            o[cc] = fmaf(fp[r0 + off], w00, fmaf(fp[r0 + off + 1], w01,
                    fmaf(fp[r1 + off], w10, fp[r1 + off + 1] * w11)));
        }
        *reinterpret_cast<f32x4*>(obase + r * 256) = o;
    }
}

extern "C" void kernel_launch(void* const* d_in, const int* in_sizes, int n_in,
                              void* d_out, int out_size, void* d_ws, size_t ws_size,
                              hipStream_t stream) {
    const float* feat = (const float*)d_in[0];
    const float* pts  = (const float*)d_in[1];
    const int*   bids = (const int*)d_in[2];
    float*       out  = (float*)d_out;

    const int n_tracks = in_sizes[2];   // 32768
    const int blocks   = (n_tracks + TPB - 1) / TPB;

    const size_t hwc_bytes =
        (size_t)N_VIEWS * H_DIM * W_DIM * C_CH * sizeof(unsigned short);

    if (ws_size >= hwc_bytes) {
        unsigned short* hwc = (unsigned short*)d_ws;
        chw_to_hwc_bf16<<<dim3(2, H_DIM, N_VIEWS), 256, 0, stream>>>(feat, hwc);
        gather_hwc<<<blocks, TPB * 64, 0, stream>>>(hwc, pts, bids, out,
                                                    n_tracks);
    } else {
        fallback_kernel<<<blocks, TPB * 64, 0, stream>>>(feat, pts, bids, out,
                                                         n_tracks);
    }
}